// Round 5
// baseline (193.839 us; speedup 1.0000x reference)
//
#include <hip/hip_runtime.h>

// Model_65678639890859 — round 5: producer/consumer overlap.
//
// Round-4 lesson: the 64-step LSTM's dependent chain costs ~20us serialized
// and ADDS to the ~18us memory stream (every block ran it before streaming).
// Now block 0 alone computes vels and publishes via agent-scope atomics to
// d_ws; all blocks issue 2 chunks (48B/thread) of stream loads FIRST, then
// spin (bounded; LSTM-local fallback => no co-residency assumption) on the
// flag. The stream flows at full BW during the LSTM: total ~= max(lstm, mem).
//
// d_ws[0..5] = vels (f32), d_ws[6] = flag word. Harness poisons d_ws to
// 0xAA before every launch, so the flag never starts equal to MAGIC.
//
// All tensors float32. Grid = 1024 blocks x 256 (4/CU).

#define V 6
#define U 4
#define SEQLEN 64
#define MAGIC 0x37C21F5Eu
#define SPIN_LIMIT 8192

__device__ __forceinline__ float frcp(float x)  { return __builtin_amdgcn_rcpf(x); }
__device__ __forceinline__ float fexp2(float x) { return __builtin_amdgcn_exp2f(x); }

__device__ __forceinline__ float sigm(float x) {
    return frcp(1.0f + fexp2(-1.442695041f * x));
}
__device__ __forceinline__ float tanh_f(float x) {
    return 1.0f - 2.0f * frcp(fexp2(2.885390082f * x) + 1.0f);
}

// DPP quad_perm: xor1 = [1,0,3,2] = 0xB1, xor2 = [2,3,0,1] = 0x4E
template <int CTRL>
__device__ __forceinline__ float qp(float x) {
    return __int_as_float(
        __builtin_amdgcn_mov_dpp(__float_as_int(x), CTRL, 0xF, 0xF, true));
}

// Per-lane LSTM; call with lane in [0,24). Returns vels for this lane
// (meaningful on u==0 lanes). Exact reference semantics:
//   step0 -> o0; vels = o0; then 63x { vels += o; x = o; step }
// => vels = 2*o0 + o1 + ... + o62 (o63 computed, discarded)
__device__ float lstm_lane(
    int lane,
    const float* __restrict__ vel,
    const float* __restrict__ Wix, const float* __restrict__ Wih, const float* __restrict__ bi,
    const float* __restrict__ Wfx, const float* __restrict__ Wfh, const float* __restrict__ bf_,
    const float* __restrict__ Wox, const float* __restrict__ Woh, const float* __restrict__ bo,
    const float* __restrict__ Wgx, const float* __restrict__ Wgh, const float* __restrict__ bg,
    const float* __restrict__ lin, const float* __restrict__ bl,
    const float* __restrict__ h0,  const float* __restrict__ c0)
{
    const int j  = lane >> 2;
    const int u  = lane & 3;
    const int r4 = lane * 4;        // row (4j+u) base into W*h weights (24x4)

    const float wix = Wix[lane], bii = bi[lane];
    const float wfx = Wfx[lane], bff = bf_[lane];
    const float wox = Wox[lane], boo = bo[lane];
    const float wgx = Wgx[lane], bgg = bg[lane];
    const float li  = lin[lane];
    const float blj = bl[j];

    // dot weights in butterfly arrival order: own(u), u^1, u^2, u^3
    const int k1 = u ^ 1, k2 = u ^ 2, k3 = u ^ 3;
    const float wi0 = Wih[r4 + u],  wi1 = Wih[r4 + k1];
    const float wi2 = Wih[r4 + k2], wi3 = Wih[r4 + k3];
    const float wf0 = Wfh[r4 + u],  wf1 = Wfh[r4 + k1];
    const float wf2 = Wfh[r4 + k2], wf3 = Wfh[r4 + k3];
    const float wo0 = Woh[r4 + u],  wo1 = Woh[r4 + k1];
    const float wo2 = Woh[r4 + k2], wo3 = Woh[r4 + k3];
    const float wg0 = Wgh[r4 + u],  wg1 = Wgh[r4 + k1];
    const float wg2 = Wgh[r4 + k2], wg3 = Wgh[r4 + k3];

    float h = h0[lane];
    float c = c0[lane];
    float x = vel[j];               // x broadcast per row

    float vels = 0.0f, o = 0.0f;

    for (int i = 0; i < SEQLEN; ++i) {
        if (i > 0) { vels += o; x = o; }

        const float hA = qp<0xB1>(h);
        const float hB = qp<0x4E>(h);
        const float hC = qp<0x4E>(hA);

        float pi = fmaf(wix, x, bii);
        pi = fmaf(wi0, h, pi); pi = fmaf(wi1, hA, pi);
        pi = fmaf(wi2, hB, pi); pi = fmaf(wi3, hC, pi);
        float pf = fmaf(wfx, x, bff);
        pf = fmaf(wf0, h, pf); pf = fmaf(wf1, hA, pf);
        pf = fmaf(wf2, hB, pf); pf = fmaf(wf3, hC, pf);
        float po = fmaf(wox, x, boo);
        po = fmaf(wo0, h, po); po = fmaf(wo1, hA, po);
        po = fmaf(wo2, hB, po); po = fmaf(wo3, hC, po);
        float pg = fmaf(wgx, x, bgg);
        pg = fmaf(wg0, h, pg); pg = fmaf(wg1, hA, pg);
        pg = fmaf(wg2, hB, pg); pg = fmaf(wg3, hC, pg);

        const float it = sigm(pi);
        const float ft = sigm(pf);
        const float ot = sigm(po);
        const float gt = sigm(pg);  // "cbar" is sigmoid in the source

        c = fmaf(ft, c, it * gt);
        h = ot * sigm(c);           // sigmoid, not tanh, as in source

        float s = li * h;
        s += qp<0xB1>(s);
        s += qp<0x4E>(s);
        o = tanh_f(s + blj);

        if (i == 0) vels = o;
    }
    return vels;
}

typedef union { float4 q[3]; float s[12]; } P12;

__device__ __forceinline__ void load12(const float* __restrict__ base, int tp, P12& d) {
    const float4* a = reinterpret_cast<const float4*>(base + (size_t)tp * 12);
    d.q[0] = a[0]; d.q[1] = a[1]; d.q[2] = a[2];
}

__device__ __forceinline__ float4 pairdot(const P12& bx, const P12& by,
                                          float v0, float v1, float v2,
                                          float v3, float v4, float v5) {
    float fx0 = bx.s[0] * v0, fy0 = by.s[0] * v0;
    float fx1 = bx.s[6] * v0, fy1 = by.s[6] * v0;
    fx0 = fmaf(bx.s[1],  v1, fx0); fy0 = fmaf(by.s[1],  v1, fy0);
    fx1 = fmaf(bx.s[7],  v1, fx1); fy1 = fmaf(by.s[7],  v1, fy1);
    fx0 = fmaf(bx.s[2],  v2, fx0); fy0 = fmaf(by.s[2],  v2, fy0);
    fx1 = fmaf(bx.s[8],  v2, fx1); fy1 = fmaf(by.s[8],  v2, fy1);
    fx0 = fmaf(bx.s[3],  v3, fx0); fy0 = fmaf(by.s[3],  v3, fy0);
    fx1 = fmaf(bx.s[9],  v3, fx1); fy1 = fmaf(by.s[9],  v3, fy1);
    fx0 = fmaf(bx.s[4],  v4, fx0); fy0 = fmaf(by.s[4],  v4, fy0);
    fx1 = fmaf(bx.s[10], v4, fx1); fy1 = fmaf(by.s[10], v4, fy1);
    fx0 = fmaf(bx.s[5],  v5, fx0); fy0 = fmaf(by.s[5],  v5, fy0);
    fx1 = fmaf(bx.s[11], v5, fx1); fy1 = fmaf(by.s[11], v5, fy1);
    float4 r; r.x = fx0; r.y = fy0; r.z = fx1; r.w = fy1;
    return r;
}

__global__ __launch_bounds__(256, 4) void fused_lstm_flow_kernel(
    const float* __restrict__ vel,
    const float* __restrict__ Wix, const float* __restrict__ Wih, const float* __restrict__ bi,
    const float* __restrict__ Wfx, const float* __restrict__ Wfh, const float* __restrict__ bf_,
    const float* __restrict__ Wox, const float* __restrict__ Woh, const float* __restrict__ bo,
    const float* __restrict__ Wgx, const float* __restrict__ Wgh, const float* __restrict__ bg,
    const float* __restrict__ lin, const float* __restrict__ bl,
    const float* __restrict__ h0,  const float* __restrict__ c0,
    const float* __restrict__ Lsx, const float* __restrict__ Lsy,
    float* __restrict__ out, int n, float* __restrict__ vg)
{
    __shared__ float vels_s[8];

    const int tid = threadIdx.x;
    const int T   = gridDim.x * blockDim.x;
    const int tp0 = blockIdx.x * blockDim.x + tid;
    const int nt  = n >> 1;                 // pixel pairs

    // ---- Issue 2 chunks of stream loads BEFORE waiting for vels ----
    const bool c0_ = tp0 < nt;
    const bool c1_ = tp0 + T < nt;
    P12 b0x, b0y, b1x, b1y;
    if (c0_) { load12(Lsx, tp0,     b0x); load12(Lsy, tp0,     b0y); }
    if (c1_) { load12(Lsx, tp0 + T, b1x); load12(Lsy, tp0 + T, b1y); }

    unsigned* flagp = (unsigned*)(vg + 6);

    if (blockIdx.x == 0) {
        // ---- Producer: LSTM on wave 0, lanes 0..23; publish vels ----
        if (tid < 24) {
            const float vl = lstm_lane(tid, vel, Wix, Wih, bi, Wfx, Wfh, bf_,
                                       Wox, Woh, bo, Wgx, Wgh, bg,
                                       lin, bl, h0, c0);
            if ((tid & 3) == 0) {
                vels_s[tid >> 2] = vl;
                __hip_atomic_store(&vg[tid >> 2], vl, __ATOMIC_RELAXED,
                                   __HIP_MEMORY_SCOPE_AGENT);
            }
        }
        if (tid == 0) {
            __hip_atomic_store(flagp, MAGIC, __ATOMIC_RELEASE,
                               __HIP_MEMORY_SCOPE_AGENT);
        }
        __syncthreads();
    } else {
        // ---- Consumer: bounded spin on flag; LSTM-local fallback ----
        if (tid == 0) {
            bool got = false;
            for (int s = 0; s < SPIN_LIMIT; ++s) {
                if (__hip_atomic_load(flagp, __ATOMIC_ACQUIRE,
                                      __HIP_MEMORY_SCOPE_AGENT) == MAGIC) {
                    got = true; break;
                }
                __builtin_amdgcn_s_sleep(2);
            }
            if (got) {
                for (int k = 0; k < 6; ++k)
                    vels_s[k] = __hip_atomic_load(&vg[k], __ATOMIC_RELAXED,
                                                  __HIP_MEMORY_SCOPE_AGENT);
            }
            vels_s[6] = got ? 1.0f : 0.0f;
        }
        __syncthreads();
        if (vels_s[6] == 0.0f) {
            // Fallback (never taken in practice): compute locally.
            if (tid < 24) {
                const float vl = lstm_lane(tid, vel, Wix, Wih, bi, Wfx, Wfh, bf_,
                                           Wox, Woh, bo, Wgx, Wgh, bg,
                                           lin, bl, h0, c0);
                if ((tid & 3) == 0) vels_s[tid >> 2] = vl;
            }
            __syncthreads();
        }
    }

    const float v0 = vels_s[0], v1 = vels_s[1], v2 = vels_s[2];
    const float v3 = vels_s[3], v4 = vels_s[4], v5 = vels_s[5];

    // ---- Phase 2: 4 statically-unrolled chunks (no register-copy pipeline) ----
    const bool c2_ = tp0 + 2 * T < nt;
    P12 b2x, b2y;
    if (c2_) { load12(Lsx, tp0 + 2 * T, b2x); load12(Lsy, tp0 + 2 * T, b2y); }

    if (c0_) reinterpret_cast<float4*>(out)[tp0] =
        pairdot(b0x, b0y, v0, v1, v2, v3, v4, v5);

    const bool c3_ = tp0 + 3 * T < nt;
    P12 b3x, b3y;
    if (c3_) { load12(Lsx, tp0 + 3 * T, b3x); load12(Lsy, tp0 + 3 * T, b3y); }

    if (c1_) reinterpret_cast<float4*>(out)[tp0 + T] =
        pairdot(b1x, b1y, v0, v1, v2, v3, v4, v5);
    if (c2_) reinterpret_cast<float4*>(out)[tp0 + 2 * T] =
        pairdot(b2x, b2y, v0, v1, v2, v3, v4, v5);
    if (c3_) reinterpret_cast<float4*>(out)[tp0 + 3 * T] =
        pairdot(b3x, b3y, v0, v1, v2, v3, v4, v5);

    // Rare remainder (nt > 4*T) — grid-stride
    for (int tp = tp0 + 4 * T; tp < nt; tp += T) {
        P12 cx, cy;
        load12(Lsx, tp, cx); load12(Lsy, tp, cy);
        reinterpret_cast<float4*>(out)[tp] =
            pairdot(cx, cy, v0, v1, v2, v3, v4, v5);
    }

    // Tail pixel if n is odd (not hit for 1920*1080)
    if ((n & 1) && blockIdx.x == 0 && tid == 0) {
        const int p = n - 1;
        float fx = 0.0f, fy = 0.0f;
        const float vv[6] = {v0, v1, v2, v3, v4, v5};
        for (int k = 0; k < 6; ++k) {
            fx = fmaf(Lsx[(size_t)p * 6 + k], vv[k], fx);
            fy = fmaf(Lsy[(size_t)p * 6 + k], vv[k], fy);
        }
        out[2 * p]     = fx;
        out[2 * p + 1] = fy;
    }
}

extern "C" void kernel_launch(void* const* d_in, const int* in_sizes, int n_in,
                              void* d_out, int out_size, void* d_ws, size_t ws_size,
                              hipStream_t stream)
{
    const float* vel  = (const float*)d_in[0];
    const float* Lsx  = (const float*)d_in[1];
    const float* Lsy  = (const float*)d_in[2];
    const float* Wix  = (const float*)d_in[3];
    const float* Wih  = (const float*)d_in[4];
    const float* bi   = (const float*)d_in[5];
    const float* Wfx  = (const float*)d_in[6];
    const float* Wfh  = (const float*)d_in[7];
    const float* bf_  = (const float*)d_in[8];
    const float* Wox  = (const float*)d_in[9];
    const float* Woh  = (const float*)d_in[10];
    const float* bo   = (const float*)d_in[11];
    const float* Wgx  = (const float*)d_in[12];
    const float* Wgh  = (const float*)d_in[13];
    const float* bg   = (const float*)d_in[14];
    const float* lin  = (const float*)d_in[15];
    const float* bl   = (const float*)d_in[16];
    const float* h0   = (const float*)d_in[17];
    const float* c0   = (const float*)d_in[18];

    const int n = in_sizes[1] / V;

    // 1024 blocks (4/CU): block 0 resident from the start => the spin
    // resolves quickly; bounded-spin fallback keeps it correct regardless.
    const int nblocks = 1024;
    fused_lstm_flow_kernel<<<nblocks, 256, 0, stream>>>(
        vel, Wix, Wih, bi, Wfx, Wfh, bf_, Wox, Woh, bo, Wgx, Wgh, bg,
        lin, bl, h0, c0, Lsx, Lsy, (float*)d_out, n, (float*)d_ws);
}

// Round 6
// 160.396 us; speedup vs baseline: 1.2085x; 1.2085x over previous
//
#include <hip/hip_runtime.h>

// Model_65678639890859 — round 6.
//
// Round-5 lesson: cross-block flag spin (agent-scope acquire loads from 1023
// blocks) floods the coherence path: 77us, VALUBusy 1.3%. Reverted.
// Round-4 lesson (from VGPR_Count=40): the compiler SANK the ~34 LSTM weight
// loads into the 64-step loop (reloading every step, ~500-800 cyc/step of
// load latency on the serial chain) — that, not ALU latency, was the ~25us
// LSTM cost. Fix: pin each weight into a VGPR with asm("" : "+v") and fence
// so weight loads issue before the chunk prefetch (their waitcnt then leaves
// the prefetch in flight).
//
// Structure: every block redundantly: [load+pin weights] -> [prefetch chunks
// 0,1 into VGPRs (fly during LSTM)] -> [wave-0 LSTM, DPP quad_perm butterflies]
// -> barrier -> 4 statically-unrolled chunk computes with chunk 2/3 loads
// overlapped. All tensors float32. Grid = 1024 x 256 (4/CU).

#define V 6
#define U 4
#define SEQLEN 64

#define PINF(x) asm volatile("" : "+v"(x))

__device__ __forceinline__ float frcp(float x)  { return __builtin_amdgcn_rcpf(x); }
__device__ __forceinline__ float fexp2(float x) { return __builtin_amdgcn_exp2f(x); }

__device__ __forceinline__ float sigm(float x) {
    return frcp(1.0f + fexp2(-1.442695041f * x));
}
__device__ __forceinline__ float tanh_f(float x) {
    return 1.0f - 2.0f * frcp(fexp2(2.885390082f * x) + 1.0f);
}

// DPP quad_perm: xor1 = [1,0,3,2] = 0xB1, xor2 = [2,3,0,1] = 0x4E
template <int CTRL>
__device__ __forceinline__ float qp(float x) {
    return __int_as_float(
        __builtin_amdgcn_mov_dpp(__float_as_int(x), CTRL, 0xF, 0xF, true));
}

typedef union { float4 q[3]; float s[12]; } P12;

__device__ __forceinline__ void load12(const float* __restrict__ base, int tp, P12& d) {
    const float4* a = reinterpret_cast<const float4*>(base + (size_t)tp * 12);
    d.q[0] = a[0]; d.q[1] = a[1]; d.q[2] = a[2];
}

__device__ __forceinline__ float4 pairdot(const P12& bx, const P12& by,
                                          float v0, float v1, float v2,
                                          float v3, float v4, float v5) {
    float fx0 = bx.s[0] * v0, fy0 = by.s[0] * v0;
    float fx1 = bx.s[6] * v0, fy1 = by.s[6] * v0;
    fx0 = fmaf(bx.s[1],  v1, fx0); fy0 = fmaf(by.s[1],  v1, fy0);
    fx1 = fmaf(bx.s[7],  v1, fx1); fy1 = fmaf(by.s[7],  v1, fy1);
    fx0 = fmaf(bx.s[2],  v2, fx0); fy0 = fmaf(by.s[2],  v2, fy0);
    fx1 = fmaf(bx.s[8],  v2, fx1); fy1 = fmaf(by.s[8],  v2, fy1);
    fx0 = fmaf(bx.s[3],  v3, fx0); fy0 = fmaf(by.s[3],  v3, fy0);
    fx1 = fmaf(bx.s[9],  v3, fx1); fy1 = fmaf(by.s[9],  v3, fy1);
    fx0 = fmaf(bx.s[4],  v4, fx0); fy0 = fmaf(by.s[4],  v4, fy0);
    fx1 = fmaf(bx.s[10], v4, fx1); fy1 = fmaf(by.s[10], v4, fy1);
    fx0 = fmaf(bx.s[5],  v5, fx0); fy0 = fmaf(by.s[5],  v5, fy0);
    fx1 = fmaf(bx.s[11], v5, fx1); fy1 = fmaf(by.s[11], v5, fy1);
    float4 r; r.x = fx0; r.y = fy0; r.z = fx1; r.w = fy1;
    return r;
}

__global__ __launch_bounds__(256, 4) void fused_lstm_flow_kernel(
    const float* __restrict__ vel,
    const float* __restrict__ Wix, const float* __restrict__ Wih, const float* __restrict__ bi,
    const float* __restrict__ Wfx, const float* __restrict__ Wfh, const float* __restrict__ bf_,
    const float* __restrict__ Wox, const float* __restrict__ Woh, const float* __restrict__ bo,
    const float* __restrict__ Wgx, const float* __restrict__ Wgh, const float* __restrict__ bg,
    const float* __restrict__ lin, const float* __restrict__ bl,
    const float* __restrict__ h0,  const float* __restrict__ c0,
    const float* __restrict__ Lsx, const float* __restrict__ Lsy,
    float* __restrict__ out, int n)
{
    __shared__ float vels_s[8];

    const int tid = threadIdx.x;
    const int T   = gridDim.x * blockDim.x;
    const int tp0 = blockIdx.x * blockDim.x + tid;
    const int nt  = n >> 1;                 // pixel pairs

    // ---- Weight loads FIRST (so their waitcnt leaves prefetch in flight),
    //      pinned into VGPRs so the compiler cannot sink them into the loop.
    float wix, bii, wfx, bff, wox, boo, wgx, bgg, li, blj;
    float wi0, wi1, wi2, wi3, wf0, wf1, wf2, wf3;
    float wo0, wo1, wo2, wo3, wg0, wg1, wg2, wg3;
    float h, c, x;

    if (tid < 24) {
        const int lane = tid;
        const int j  = lane >> 2;
        const int u  = lane & 3;
        const int r4 = lane * 4;        // row (4j+u) base into W*h weights (24x4)
        const int k1 = u ^ 1, k2 = u ^ 2, k3 = u ^ 3;

        wix = Wix[lane]; bii = bi[lane];
        wfx = Wfx[lane]; bff = bf_[lane];
        wox = Wox[lane]; boo = bo[lane];
        wgx = Wgx[lane]; bgg = bg[lane];
        li  = lin[lane]; blj = bl[j];

        // dot weights in butterfly arrival order: own(u), u^1, u^2, u^3
        wi0 = Wih[r4 + u];  wi1 = Wih[r4 + k1];
        wi2 = Wih[r4 + k2]; wi3 = Wih[r4 + k3];
        wf0 = Wfh[r4 + u];  wf1 = Wfh[r4 + k1];
        wf2 = Wfh[r4 + k2]; wf3 = Wfh[r4 + k3];
        wo0 = Woh[r4 + u];  wo1 = Woh[r4 + k1];
        wo2 = Woh[r4 + k2]; wo3 = Woh[r4 + k3];
        wg0 = Wgh[r4 + u];  wg1 = Wgh[r4 + k1];
        wg2 = Wgh[r4 + k2]; wg3 = Wgh[r4 + k3];

        h = h0[lane]; c = c0[lane]; x = vel[j];

        PINF(wix); PINF(bii); PINF(wfx); PINF(bff);
        PINF(wox); PINF(boo); PINF(wgx); PINF(bgg);
        PINF(li);  PINF(blj);
        PINF(wi0); PINF(wi1); PINF(wi2); PINF(wi3);
        PINF(wf0); PINF(wf1); PINF(wf2); PINF(wf3);
        PINF(wo0); PINF(wo1); PINF(wo2); PINF(wo3);
        PINF(wg0); PINF(wg1); PINF(wg2); PINF(wg3);
        PINF(h); PINF(c); PINF(x);
    }

    // Fence: chunk prefetch below must not be hoisted above the weight loads.
    asm volatile("" ::: "memory");

    // ---- Prefetch chunks 0,1 (fly during the LSTM) ----
    const bool c0_ = tp0 < nt;
    const bool c1_ = tp0 + T < nt;
    P12 b0x, b0y, b1x, b1y;
    if (c0_) { load12(Lsx, tp0,     b0x); load12(Lsy, tp0,     b0y); }
    if (c1_) { load12(Lsx, tp0 + T, b1x); load12(Lsy, tp0 + T, b1y); }

    // ---- Phase 1: LSTM on wave 0, lanes 0..23 (pinned weights) ----
    // Exact reference semantics:
    //   step0 -> o0; vels = o0; then 63x { vels += o; x = o; step }
    // => vels = 2*o0 + o1 + ... + o62 (o63 computed, discarded)
    if (tid < 24) {
        float vels = 0.0f, o = 0.0f;

        for (int i = 0; i < SEQLEN; ++i) {
            if (i > 0) { vels += o; x = o; }

            const float hA = qp<0xB1>(h);
            const float hB = qp<0x4E>(h);
            const float hC = qp<0x4E>(hA);

            float pi = fmaf(wix, x, bii);
            pi = fmaf(wi0, h, pi); pi = fmaf(wi1, hA, pi);
            pi = fmaf(wi2, hB, pi); pi = fmaf(wi3, hC, pi);
            float pf = fmaf(wfx, x, bff);
            pf = fmaf(wf0, h, pf); pf = fmaf(wf1, hA, pf);
            pf = fmaf(wf2, hB, pf); pf = fmaf(wf3, hC, pf);
            float po = fmaf(wox, x, boo);
            po = fmaf(wo0, h, po); po = fmaf(wo1, hA, po);
            po = fmaf(wo2, hB, po); po = fmaf(wo3, hC, po);
            float pg = fmaf(wgx, x, bgg);
            pg = fmaf(wg0, h, pg); pg = fmaf(wg1, hA, pg);
            pg = fmaf(wg2, hB, pg); pg = fmaf(wg3, hC, pg);

            const float it = sigm(pi);
            const float ft = sigm(pf);
            const float ot = sigm(po);
            const float gt = sigm(pg);  // "cbar" is sigmoid in the source

            c = fmaf(ft, c, it * gt);
            h = ot * sigm(c);           // sigmoid, not tanh, as in source

            float s = li * h;
            s += qp<0xB1>(s);
            s += qp<0x4E>(s);
            o = tanh_f(s + blj);

            if (i == 0) vels = o;
        }

        if ((tid & 3) == 0) vels_s[tid >> 2] = vels;
    }

    __syncthreads();

    const float v0 = vels_s[0], v1 = vels_s[1], v2 = vels_s[2];
    const float v3 = vels_s[3], v4 = vels_s[4], v5 = vels_s[5];

    // ---- Phase 2: 4 statically-unrolled chunks ----
    const bool c2_ = tp0 + 2 * T < nt;
    P12 b2x, b2y;
    if (c2_) { load12(Lsx, tp0 + 2 * T, b2x); load12(Lsy, tp0 + 2 * T, b2y); }

    if (c0_) reinterpret_cast<float4*>(out)[tp0] =
        pairdot(b0x, b0y, v0, v1, v2, v3, v4, v5);

    const bool c3_ = tp0 + 3 * T < nt;
    P12 b3x, b3y;
    if (c3_) { load12(Lsx, tp0 + 3 * T, b3x); load12(Lsy, tp0 + 3 * T, b3y); }

    if (c1_) reinterpret_cast<float4*>(out)[tp0 + T] =
        pairdot(b1x, b1y, v0, v1, v2, v3, v4, v5);
    if (c2_) reinterpret_cast<float4*>(out)[tp0 + 2 * T] =
        pairdot(b2x, b2y, v0, v1, v2, v3, v4, v5);
    if (c3_) reinterpret_cast<float4*>(out)[tp0 + 3 * T] =
        pairdot(b3x, b3y, v0, v1, v2, v3, v4, v5);

    // Rare remainder (nt > 4*T) — grid-stride
    for (int tp = tp0 + 4 * T; tp < nt; tp += T) {
        P12 cx, cy;
        load12(Lsx, tp, cx); load12(Lsy, tp, cy);
        reinterpret_cast<float4*>(out)[tp] =
            pairdot(cx, cy, v0, v1, v2, v3, v4, v5);
    }

    // Tail pixel if n is odd (not hit for 1920*1080)
    if ((n & 1) && blockIdx.x == 0 && tid == 0) {
        const int p = n - 1;
        float fx = 0.0f, fy = 0.0f;
        const float vv[6] = {v0, v1, v2, v3, v4, v5};
        for (int k = 0; k < 6; ++k) {
            fx = fmaf(Lsx[(size_t)p * 6 + k], vv[k], fx);
            fy = fmaf(Lsy[(size_t)p * 6 + k], vv[k], fy);
        }
        out[2 * p]     = fx;
        out[2 * p + 1] = fy;
    }
}

extern "C" void kernel_launch(void* const* d_in, const int* in_sizes, int n_in,
                              void* d_out, int out_size, void* d_ws, size_t ws_size,
                              hipStream_t stream)
{
    const float* vel  = (const float*)d_in[0];
    const float* Lsx  = (const float*)d_in[1];
    const float* Lsy  = (const float*)d_in[2];
    const float* Wix  = (const float*)d_in[3];
    const float* Wih  = (const float*)d_in[4];
    const float* bi   = (const float*)d_in[5];
    const float* Wfx  = (const float*)d_in[6];
    const float* Wfh  = (const float*)d_in[7];
    const float* bf_  = (const float*)d_in[8];
    const float* Wox  = (const float*)d_in[9];
    const float* Woh  = (const float*)d_in[10];
    const float* bo   = (const float*)d_in[11];
    const float* Wgx  = (const float*)d_in[12];
    const float* Wgh  = (const float*)d_in[13];
    const float* bg   = (const float*)d_in[14];
    const float* lin  = (const float*)d_in[15];
    const float* bl   = (const float*)d_in[16];
    const float* h0   = (const float*)d_in[17];
    const float* c0   = (const float*)d_in[18];

    const int n = in_sizes[1] / V;

    const int nblocks = 1024;   // 4/CU, one residency round
    fused_lstm_flow_kernel<<<nblocks, 256, 0, stream>>>(
        vel, Wix, Wih, bi, Wfx, Wfh, bf_, Wox, Woh, bo, Wgx, Wgh, bg,
        lin, bl, h0, c0, Lsx, Lsy, (float*)d_out, n);
}

// Round 7
// 157.007 us; speedup vs baseline: 1.2346x; 1.0216x over previous
//
#include <hip/hip_runtime.h>

// Model_65678639890859 — round 7: kill the phase-2 register spills.
//
// r6 win: pinning LSTM weights in VGPRs (compiler had sunk ~34 weight loads
// into the 64-step loop) took the kernel below the 40us profiling bar
// (~34us by dur_us subtraction). Remaining gap vs ~16-20us ideal: r6's
// phase-2 schedule had 3 chunks x 48 VGPRs = 144 data regs live (+27 pinned
// weights) against the 128-reg cap of __launch_bounds__(256,4) => scratch
// spills, ~100MB hidden traffic machine-wide.
//
// r7 structure (max 2 chunks = 96 data regs live anywhere):
//   wave 0   : load+pin weights, prefetch chunk0, LSTM (lanes 0..23, DPP
//              quad_perm), publish vels to LDS.
//   waves 1-3: prefetch chunks 0 AND 1 (no weights live) -> ~37MB in flight
//              machine-wide hides the LSTM behind the drain.
//   barrier; wave 0 loads chunk1; then all: compute c0, load c2, compute c1,
//   load c3, compute c2, compute c3 (+grid-stride remainder).
//
// All tensors float32. Grid = 1024 x 256 (4/CU, one residency round).

#define V 6
#define U 4
#define SEQLEN 64

#define PINF(x) asm volatile("" : "+v"(x))

__device__ __forceinline__ float frcp(float x)  { return __builtin_amdgcn_rcpf(x); }
__device__ __forceinline__ float fexp2(float x) { return __builtin_amdgcn_exp2f(x); }

__device__ __forceinline__ float sigm(float x) {
    return frcp(1.0f + fexp2(-1.442695041f * x));
}
__device__ __forceinline__ float tanh_f(float x) {
    return 1.0f - 2.0f * frcp(fexp2(2.885390082f * x) + 1.0f);
}

// DPP quad_perm: xor1 = [1,0,3,2] = 0xB1, xor2 = [2,3,0,1] = 0x4E
template <int CTRL>
__device__ __forceinline__ float qp(float x) {
    return __int_as_float(
        __builtin_amdgcn_mov_dpp(__float_as_int(x), CTRL, 0xF, 0xF, true));
}

typedef union { float4 q[3]; float s[12]; } P12;

__device__ __forceinline__ void load12(const float* __restrict__ base, int tp, P12& d) {
    const float4* a = reinterpret_cast<const float4*>(base + (size_t)tp * 12);
    d.q[0] = a[0]; d.q[1] = a[1]; d.q[2] = a[2];
}

__device__ __forceinline__ float4 pairdot(const P12& bx, const P12& by,
                                          float v0, float v1, float v2,
                                          float v3, float v4, float v5) {
    float fx0 = bx.s[0] * v0, fy0 = by.s[0] * v0;
    float fx1 = bx.s[6] * v0, fy1 = by.s[6] * v0;
    fx0 = fmaf(bx.s[1],  v1, fx0); fy0 = fmaf(by.s[1],  v1, fy0);
    fx1 = fmaf(bx.s[7],  v1, fx1); fy1 = fmaf(by.s[7],  v1, fy1);
    fx0 = fmaf(bx.s[2],  v2, fx0); fy0 = fmaf(by.s[2],  v2, fy0);
    fx1 = fmaf(bx.s[8],  v2, fx1); fy1 = fmaf(by.s[8],  v2, fy1);
    fx0 = fmaf(bx.s[3],  v3, fx0); fy0 = fmaf(by.s[3],  v3, fy0);
    fx1 = fmaf(bx.s[9],  v3, fx1); fy1 = fmaf(by.s[9],  v3, fy1);
    fx0 = fmaf(bx.s[4],  v4, fx0); fy0 = fmaf(by.s[4],  v4, fy0);
    fx1 = fmaf(bx.s[10], v4, fx1); fy1 = fmaf(by.s[10], v4, fy1);
    fx0 = fmaf(bx.s[5],  v5, fx0); fy0 = fmaf(by.s[5],  v5, fy0);
    fx1 = fmaf(bx.s[11], v5, fx1); fy1 = fmaf(by.s[11], v5, fy1);
    float4 r; r.x = fx0; r.y = fy0; r.z = fx1; r.w = fy1;
    return r;
}

__global__ __launch_bounds__(256, 4) void fused_lstm_flow_kernel(
    const float* __restrict__ vel,
    const float* __restrict__ Wix, const float* __restrict__ Wih, const float* __restrict__ bi,
    const float* __restrict__ Wfx, const float* __restrict__ Wfh, const float* __restrict__ bf_,
    const float* __restrict__ Wox, const float* __restrict__ Woh, const float* __restrict__ bo,
    const float* __restrict__ Wgx, const float* __restrict__ Wgh, const float* __restrict__ bg,
    const float* __restrict__ lin, const float* __restrict__ bl,
    const float* __restrict__ h0,  const float* __restrict__ c0,
    const float* __restrict__ Lsx, const float* __restrict__ Lsy,
    float* __restrict__ out, int n)
{
    __shared__ float vels_s[8];

    const int tid = threadIdx.x;
    const int T   = gridDim.x * blockDim.x;
    const int tp0 = blockIdx.x * blockDim.x + tid;
    const int nt  = n >> 1;                 // pixel pairs
    const bool w0 = tid < 64;               // wave-uniform

    const bool cc0 = tp0 < nt;
    const bool cc1 = tp0 + T < nt;

    // ---- Wave 0: weight loads FIRST, pinned (cannot be sunk into the loop).
    float wix, bii, wfx, bff, wox, boo, wgx, bgg, li, blj;
    float wi0, wi1, wi2, wi3, wf0, wf1, wf2, wf3;
    float wo0, wo1, wo2, wo3, wg0, wg1, wg2, wg3;
    float h, c, x;

    if (w0 && tid < 24) {
        const int lane = tid;
        const int j  = lane >> 2;
        const int u  = lane & 3;
        const int r4 = lane * 4;        // row (4j+u) base into W*h weights (24x4)
        const int k1 = u ^ 1, k2 = u ^ 2, k3 = u ^ 3;

        wix = Wix[lane]; bii = bi[lane];
        wfx = Wfx[lane]; bff = bf_[lane];
        wox = Wox[lane]; boo = bo[lane];
        wgx = Wgx[lane]; bgg = bg[lane];
        li  = lin[lane]; blj = bl[j];

        // dot weights in butterfly arrival order: own(u), u^1, u^2, u^3
        wi0 = Wih[r4 + u];  wi1 = Wih[r4 + k1];
        wi2 = Wih[r4 + k2]; wi3 = Wih[r4 + k3];
        wf0 = Wfh[r4 + u];  wf1 = Wfh[r4 + k1];
        wf2 = Wfh[r4 + k2]; wf3 = Wfh[r4 + k3];
        wo0 = Woh[r4 + u];  wo1 = Woh[r4 + k1];
        wo2 = Woh[r4 + k2]; wo3 = Woh[r4 + k3];
        wg0 = Wgh[r4 + u];  wg1 = Wgh[r4 + k1];
        wg2 = Wgh[r4 + k2]; wg3 = Wgh[r4 + k3];

        h = h0[lane]; c = c0[lane]; x = vel[j];

        PINF(wix); PINF(bii); PINF(wfx); PINF(bff);
        PINF(wox); PINF(boo); PINF(wgx); PINF(bgg);
        PINF(li);  PINF(blj);
        PINF(wi0); PINF(wi1); PINF(wi2); PINF(wi3);
        PINF(wf0); PINF(wf1); PINF(wf2); PINF(wf3);
        PINF(wo0); PINF(wo1); PINF(wo2); PINF(wo3);
        PINF(wg0); PINF(wg1); PINF(wg2); PINF(wg3);
        PINF(h); PINF(c); PINF(x);
    }

    // Fence: chunk prefetch must not be hoisted above the weight loads
    // (weights issued first => their waitcnt leaves chunk loads in flight).
    asm volatile("" ::: "memory");

    // ---- Prefetch: chunk 0 everywhere; chunk 1 only on waves 1-3 (keeps
    //      wave-0 pressure low while weights are live).
    P12 b0x, b0y, b1x, b1y;
    if (cc0) { load12(Lsx, tp0, b0x); load12(Lsy, tp0, b0y); }
    if (!w0 && cc1) { load12(Lsx, tp0 + T, b1x); load12(Lsy, tp0 + T, b1y); }

    // ---- Phase 1: LSTM on wave 0, lanes 0..23 (pinned weights) ----
    // Exact reference semantics:
    //   step0 -> o0; vels = o0; then 63x { vels += o; x = o; step }
    // => vels = 2*o0 + o1 + ... + o62 (o63 computed, discarded)
    if (w0 && tid < 24) {
        float vels = 0.0f, o = 0.0f;

        for (int i = 0; i < SEQLEN; ++i) {
            if (i > 0) { vels += o; x = o; }

            const float hA = qp<0xB1>(h);
            const float hB = qp<0x4E>(h);
            const float hC = qp<0x4E>(hA);

            float pi = fmaf(wix, x, bii);
            pi = fmaf(wi0, h, pi); pi = fmaf(wi1, hA, pi);
            pi = fmaf(wi2, hB, pi); pi = fmaf(wi3, hC, pi);
            float pf = fmaf(wfx, x, bff);
            pf = fmaf(wf0, h, pf); pf = fmaf(wf1, hA, pf);
            pf = fmaf(wf2, hB, pf); pf = fmaf(wf3, hC, pf);
            float po = fmaf(wox, x, boo);
            po = fmaf(wo0, h, po); po = fmaf(wo1, hA, po);
            po = fmaf(wo2, hB, po); po = fmaf(wo3, hC, po);
            float pg = fmaf(wgx, x, bgg);
            pg = fmaf(wg0, h, pg); pg = fmaf(wg1, hA, pg);
            pg = fmaf(wg2, hB, pg); pg = fmaf(wg3, hC, pg);

            const float it = sigm(pi);
            const float ft = sigm(pf);
            const float ot = sigm(po);
            const float gt = sigm(pg);  // "cbar" is sigmoid in the source

            c = fmaf(ft, c, it * gt);
            h = ot * sigm(c);           // sigmoid, not tanh, as in source

            float s = li * h;
            s += qp<0xB1>(s);
            s += qp<0x4E>(s);
            o = tanh_f(s + blj);

            if (i == 0) vels = o;
        }

        if ((tid & 3) == 0) vels_s[tid >> 2] = vels;
    }

    __syncthreads();

    const float v0 = vels_s[0], v1 = vels_s[1], v2 = vels_s[2];
    const float v3 = vels_s[3], v4 = vels_s[4], v5 = vels_s[5];

    // Wave 0 catches up on its chunk-1 load (weights now dead).
    if (w0 && cc1) { load12(Lsx, tp0 + T, b1x); load12(Lsy, tp0 + T, b1y); }

    // ---- Phase 2: strict 2-live-chunk schedule (96 data VGPRs max) ----
    if (cc0) reinterpret_cast<float4*>(out)[tp0] =
        pairdot(b0x, b0y, v0, v1, v2, v3, v4, v5);        // c0 dies

    const bool cc2 = tp0 + 2 * T < nt;
    P12 b2x, b2y;
    if (cc2) { load12(Lsx, tp0 + 2 * T, b2x); load12(Lsy, tp0 + 2 * T, b2y); }

    if (cc1) reinterpret_cast<float4*>(out)[tp0 + T] =
        pairdot(b1x, b1y, v0, v1, v2, v3, v4, v5);        // c1 dies

    const bool cc3 = tp0 + 3 * T < nt;
    P12 b3x, b3y;
    if (cc3) { load12(Lsx, tp0 + 3 * T, b3x); load12(Lsy, tp0 + 3 * T, b3y); }

    if (cc2) reinterpret_cast<float4*>(out)[tp0 + 2 * T] =
        pairdot(b2x, b2y, v0, v1, v2, v3, v4, v5);        // c2 dies

    if (cc3) reinterpret_cast<float4*>(out)[tp0 + 3 * T] =
        pairdot(b3x, b3y, v0, v1, v2, v3, v4, v5);

    // Rare remainder (nt > 4*T) — grid-stride
    for (int tp = tp0 + 4 * T; tp < nt; tp += T) {
        P12 cx, cy;
        load12(Lsx, tp, cx); load12(Lsy, tp, cy);
        reinterpret_cast<float4*>(out)[tp] =
            pairdot(cx, cy, v0, v1, v2, v3, v4, v5);
    }

    // Tail pixel if n is odd (not hit for 1920*1080)
    if ((n & 1) && blockIdx.x == 0 && tid == 0) {
        const int p = n - 1;
        float fx = 0.0f, fy = 0.0f;
        const float vv[6] = {v0, v1, v2, v3, v4, v5};
        for (int k = 0; k < 6; ++k) {
            fx = fmaf(Lsx[(size_t)p * 6 + k], vv[k], fx);
            fy = fmaf(Lsy[(size_t)p * 6 + k], vv[k], fy);
        }
        out[2 * p]     = fx;
        out[2 * p + 1] = fy;
    }
}

extern "C" void kernel_launch(void* const* d_in, const int* in_sizes, int n_in,
                              void* d_out, int out_size, void* d_ws, size_t ws_size,
                              hipStream_t stream)
{
    const float* vel  = (const float*)d_in[0];
    const float* Lsx  = (const float*)d_in[1];
    const float* Lsy  = (const float*)d_in[2];
    const float* Wix  = (const float*)d_in[3];
    const float* Wih  = (const float*)d_in[4];
    const float* bi   = (const float*)d_in[5];
    const float* Wfx  = (const float*)d_in[6];
    const float* Wfh  = (const float*)d_in[7];
    const float* bf_  = (const float*)d_in[8];
    const float* Wox  = (const float*)d_in[9];
    const float* Woh  = (const float*)d_in[10];
    const float* bo   = (const float*)d_in[11];
    const float* Wgx  = (const float*)d_in[12];
    const float* Wgh  = (const float*)d_in[13];
    const float* bg   = (const float*)d_in[14];
    const float* lin  = (const float*)d_in[15];
    const float* bl   = (const float*)d_in[16];
    const float* h0   = (const float*)d_in[17];
    const float* c0   = (const float*)d_in[18];

    const int n = in_sizes[1] / V;

    const int nblocks = 1024;   // 4/CU, one residency round
    fused_lstm_flow_kernel<<<nblocks, 256, 0, stream>>>(
        vel, Wix, Wih, bi, Wfx, Wfh, bf_, Wox, Woh, bo, Wgx, Wgh, bg,
        lin, bl, h0, c0, Lsx, Lsy, (float*)d_out, n);
}